// Round 8
// baseline (364.775 us; speedup 1.0000x reference)
//
#include <hip/hip_runtime.h>
#include <math.h>

#define BB 4
#define NN 4096
#define DD 64
#define KK 8
#define CH 4                    // j-chunks per row: grid = 4*32*4 = 512 blocks
#define NT ((NN / CH) / 64)     // 16 j-tiles per block
#define IT 128                  // i-tile rows per block

#if defined(__has_builtin)
#if __has_builtin(__builtin_amdgcn_fmed3f)
#define FMED3(a, x, b) __builtin_amdgcn_fmed3f((x), (a), (b))
#endif
#endif
#ifndef FMED3
#define FMED3(a, x, b) fminf(fmaxf((a), (x)), (b))
#endif

__device__ __forceinline__ float tau_of(const float* __restrict__ temp) {
  float tc = temp[0];
  tc = fminf(fmaxf(tc, -5.0f), 5.0f);
  return expf(tc);
}

// Branch-free positional insert into sorted (ascending) top-8.
// All updates read OLD values -> fully parallel. key >= kk[7] is a no-op.
// Equal keys place AFTER incumbents (matches ascending-j arrival semantics).
// NOTE: reference-to-1-D-array signature is load-bearing (SROA).
__device__ __forceinline__ void ins_med3(float (&kk)[KK], int (&kj)[KK], float key, int j) {
  const bool l0 = key < kk[0], l1 = key < kk[1], l2 = key < kk[2], l3 = key < kk[3];
  const bool l4 = key < kk[4], l5 = key < kk[5], l6 = key < kk[6], l7 = key < kk[7];
  kj[7] = l6 ? kj[6] : (l7 ? j : kj[7]);  kk[7] = FMED3(kk[6], key, kk[7]);
  kj[6] = l5 ? kj[5] : (l6 ? j : kj[6]);  kk[6] = FMED3(kk[5], key, kk[6]);
  kj[5] = l4 ? kj[4] : (l5 ? j : kj[5]);  kk[5] = FMED3(kk[4], key, kk[5]);
  kj[4] = l3 ? kj[3] : (l4 ? j : kj[4]);  kk[4] = FMED3(kk[3], key, kk[4]);
  kj[3] = l2 ? kj[2] : (l3 ? j : kj[3]);  kk[3] = FMED3(kk[2], key, kk[3]);
  kj[2] = l1 ? kj[1] : (l2 ? j : kj[2]);  kk[2] = FMED3(kk[1], key, kk[2]);
  kj[1] = l0 ? kj[0] : (l1 ? j : kj[1]);  kk[1] = FMED3(kk[0], key, kk[1]);
  kj[0] = l0 ? j : kj[0];                 kk[0] = fminf(kk[0], key);
}

// lexicographic (key asc, idx asc) insertion — arrival order independent.
__device__ __forceinline__ void ins_lex(float (&kk)[KK], int (&kj)[KK], float key, int j) {
  if (key < kk[KK - 1] || (key == kk[KK - 1] && j < kj[KK - 1])) {
    kk[KK - 1] = key; kj[KK - 1] = j;
#pragma unroll
    for (int m = KK - 1; m > 0; --m) {
      bool sw = (kk[m] < kk[m - 1]) || (kk[m] == kk[m - 1] && kj[m] < kj[m - 1]);
      if (sw) {
        float tk = kk[m]; kk[m] = kk[m - 1]; kk[m - 1] = tk;
        int tj = kj[m]; kj[m] = kj[m - 1]; kj[m - 1] = tj;
      }
    }
  }
}

__device__ __forceinline__ void scat4i(float (*dst)[IT], int d0, int col, const float4& v) {
  dst[d0 + 0][col] = v.x; dst[d0 + 1][col] = v.y; dst[d0 + 2][col] = v.z; dst[d0 + 3][col] = v.w;
}
__device__ __forceinline__ void scat4j(float (*dst)[64], int d0, int col, const float4& v) {
  dst[d0 + 0][col] = v.x; dst[d0 + 1][col] = v.y; dst[d0 + 2][col] = v.z; dst[d0 + 3][col] = v.w;
}

// ---------------- Kernel 1: MLP (3 layers) + row squared norms ----------------
__device__ __forceinline__ void mlp_layer(const float (*bin)[68], float (*bout)[68],
                                          float (*wT)[68], float* bias,
                                          const float* __restrict__ Wg,
                                          const float* __restrict__ bg,
                                          bool dorelu, int t) {
  const int rr = t >> 2;
  const int dc = (t & 3) << 4;
  {
    const float* wsrc = Wg + rr * DD + dc;
#pragma unroll
    for (int q = 0; q < 16; ++q) wT[dc + q][rr] = wsrc[q];  // wT[i][o] = W[o][i]
    if (t < DD) bias[t] = bg[t];
  }
  __syncthreads();
  const int tg = t & 15, og = t >> 4;
  float acc[4][4];
#pragma unroll
  for (int r = 0; r < 4; ++r)
#pragma unroll
    for (int c = 0; c < 4; ++c) acc[r][c] = 0.f;
#pragma unroll 4
  for (int i = 0; i < DD; ++i) {
    const float4 av = *reinterpret_cast<const float4*>(&bin[i][tg << 2]);
    const float4 wv = *reinterpret_cast<const float4*>(&wT[i][og << 2]);
    float aa[4] = {av.x, av.y, av.z, av.w};
    float ww[4] = {wv.x, wv.y, wv.z, wv.w};
#pragma unroll
    for (int r = 0; r < 4; ++r)
#pragma unroll
      for (int c = 0; c < 4; ++c) acc[r][c] += aa[r] * ww[c];
  }
#pragma unroll
  for (int r = 0; r < 4; ++r)
#pragma unroll
    for (int c = 0; c < 4; ++c) {
      float v = acc[r][c] + bias[(og << 2) + c];
      if (dorelu) v = fmaxf(v, 0.f);
      bout[(og << 2) + c][(tg << 2) + r] = v;  // transposed for next layer
    }
  __syncthreads();
}

__global__ __launch_bounds__(256) void k_mlp(
    const float* __restrict__ x,
    const float* __restrict__ W1, const float* __restrict__ b1,
    const float* __restrict__ W2, const float* __restrict__ b2,
    const float* __restrict__ W3, const float* __restrict__ b3,
    float* __restrict__ h, float* __restrict__ sqo) {
  __shared__ float bufA[DD][68];
  __shared__ float bufB[DD][68];
  __shared__ float wT[DD][68];
  __shared__ float bias[DD];
  const int t = threadIdx.x;
  const size_t tok0 = (size_t)blockIdx.x * 64;
  const int rr = t >> 2;
  const int dc = (t & 3) << 4;
  {
    const float* src = x + (tok0 + rr) * DD + dc;
#pragma unroll
    for (int q = 0; q < 16; ++q) bufA[dc + q][rr] = src[q];
  }
  mlp_layer(bufA, bufB, wT, bias, W1, b1, true, t);
  mlp_layer(bufB, bufA, wT, bias, W2, b2, true, t);
  mlp_layer(bufA, bufB, wT, bias, W3, b3, false, t);
  {
    float s = 0.f;
    float* dst = h + (tok0 + rr) * DD + dc;
#pragma unroll
    for (int q = 0; q < 16; ++q) {
      float v = bufB[dc + q][rr];
      dst[q] = v;
      s += v * v;
    }
    s += __shfl_xor(s, 1);
    s += __shfl_xor(s, 2);
    if ((t & 3) == 0) sqo[tok0 + rr] = s;
  }
}

// ---- Kernel 2 helper: merge 64 rows x 8 lane-lists from LDS dump -> pk/pj ----
// Touches ONLY LDS + globals (no register lists) so it can't break SROA.
__device__ __forceinline__ void merge64(char* smem, int t, int rowOff,
                                        int b, int i0, int ch,
                                        float* __restrict__ pk, int* __restrict__ pj) {
  float* dK = (float*)(smem);            // [64][8][8] keys (16KB)
  int*   dJ = (int*)(smem + 16384);      // [64][8][8] idx  (16KB)
  float* oK = (float*)(smem);            // [64][2][8] keys (4KB, reused after sync)
  int*   oJ = (int*)(smem + 4096);       // [64][2][8] idx  (4KB)
  __syncthreads();  // dump visible
  float fk[KK]; int fj[KK];
#pragma unroll
  for (int m = 0; m < KK; ++m) { fk[m] = 3.0e38f; fj[m] = 0x7fffffff; }
  const int rowA = t >> 1, half = t & 1;
  if (t < 128) {
#pragma unroll
    for (int o = 0; o < 4; ++o)
#pragma unroll
      for (int m = 0; m < KK; ++m)
        ins_lex(fk, fj, dK[(rowA * 8 + half * 4 + o) * KK + m],
                        dJ[(rowA * 8 + half * 4 + o) * KK + m]);
  }
  __syncthreads();  // stage-A reads complete before oK overwrite
  if (t < 128) {
#pragma unroll
    for (int m = 0; m < KK; ++m) {
      oK[(rowA * 2 + half) * KK + m] = fk[m];
      oJ[(rowA * 2 + half) * KK + m] = fj[m];
    }
  }
  __syncthreads();
  if (t < 64) {
    float gk[KK]; int gj[KK];
#pragma unroll
    for (int m = 0; m < KK; ++m) { gk[m] = 3.0e38f; gj[m] = 0x7fffffff; }
#pragma unroll
    for (int q = 0; q < 2; ++q)
#pragma unroll
      for (int m = 0; m < KK; ++m)
        ins_lex(gk, gj, oK[(t * 2 + q) * KK + m], oJ[(t * 2 + q) * KK + m]);
    const int grow = ((t >> 1) << 2) + (t & 1) + rowOff;
    const size_t base = ((size_t)(b * NN + i0 + grow) * CH + ch) * KK;
#pragma unroll
    for (int m = 0; m < KK; ++m) { pk[base + m] = gk[m]; pj[base + m] = gj[m]; }
  }
  __syncthreads();  // protect dK region from the next pass's dump
}

// ------- Kernel 2: 128x64 block tiles, 4x8 register tile, per-row top-8 -------
// Thread (rg,cg): rows r0..r0+3 (r0=rg*4, 0..127), cols c0..c0+7 (c0=cg*8).
// LDS bytes/FMA cut 0.625->0.375 float (A is one conflict-free b128 for 4 rows).
__global__ __launch_bounds__(256, 3) void k_disttopk(
    const float* __restrict__ h, const float* __restrict__ sq,
    const float* __restrict__ temp,
    float* __restrict__ pk, int* __restrict__ pj) {
  // LDS: hiT [64][128] @0 (32KB) | hjT [64][64] @32768 (16KB) | sqjS [64] @49152
  // merge reuses bytes 0..32767 (dK/dJ then oK/oJ)
  __shared__ __align__(16) char smem[32768 + 16384 + 256];
  float (*hiT)[IT] = (float (*)[IT])(smem);
  float (*hjT)[64] = (float (*)[64])(smem + 32768);
  float* sqjS = (float*)(smem + 49152);  // [64]

  const int t = threadIdx.x;
  const int bx = blockIdx.x;
  const int b = bx >> 7;          // 128 blocks per batch (32 rt x 4 ch)
  const int rem = bx & 127;
  const int rt = rem >> 2;        // 0..31
  const int ch = rem & 3;
  const int i0 = rt << 7;         // 128-row i-tile
  const int jbase = ch * (NN / CH);
  const float* hb = h + (size_t)b * NN * DD;
  const float* sqb = sq + b * NN;
  const float tau = tau_of(temp);

  const int rg = t >> 3;          // 0..31
  const int cg = t & 7;           // 0..7
  const int r0 = rg << 2;         // 4 rows per thread
  const int c0 = cg << 3;         // 8 cols per thread
  // hjT staging: lane stages 16 d-floats of one token (banks tok%32 -> 2-way, free)
  const int tokJ = t & 63;
  const int dhJ = (t >> 6) << 4;  // 0,16,32,48

  // ---- stage hiT [d][tok], 128 tokens: lane stages 32 d-floats of one token ----
  {
    const int tok = t & 127;
    const int dh = (t >> 7) << 5;  // 0 or 32
    const float* src = hb + (size_t)(i0 + tok) * DD + dh;
    const float4 g0 = *(const float4*)(src);
    const float4 g1 = *(const float4*)(src + 4);
    const float4 g2 = *(const float4*)(src + 8);
    const float4 g3 = *(const float4*)(src + 12);
    const float4 g4 = *(const float4*)(src + 16);
    const float4 g5 = *(const float4*)(src + 20);
    const float4 g6 = *(const float4*)(src + 24);
    const float4 g7 = *(const float4*)(src + 28);
    scat4i(hiT, dh + 0, tok, g0);  scat4i(hiT, dh + 4, tok, g1);
    scat4i(hiT, dh + 8, tok, g2);  scat4i(hiT, dh + 12, tok, g3);
    scat4i(hiT, dh + 16, tok, g4); scat4i(hiT, dh + 20, tok, g5);
    scat4i(hiT, dh + 24, tok, g6); scat4i(hiT, dh + 28, tok, g7);
  }
  // ---- stage hjT tile 0 + sqjS ----
  {
    const float* src = hb + (size_t)(jbase + tokJ) * DD + dhJ;
    const float4 g0 = *(const float4*)(src);
    const float4 g1 = *(const float4*)(src + 4);
    const float4 g2 = *(const float4*)(src + 8);
    const float4 g3 = *(const float4*)(src + 12);
    scat4j(hjT, dhJ + 0, tokJ, g0);  scat4j(hjT, dhJ + 4, tokJ, g1);
    scat4j(hjT, dhJ + 8, tokJ, g2);  scat4j(hjT, dhJ + 12, tokJ, g3);
    if (t < 64) sqjS[t] = sqb[jbase + t];
  }
  const float sqi0 = sqb[i0 + r0 + 0];
  const float sqi1 = sqb[i0 + r0 + 1];
  const float sqi2 = sqb[i0 + r0 + 2];
  const float sqi3 = sqb[i0 + r0 + 3];

  float kk0[KK], kk1[KK], kk2[KK], kk3[KK];
  int kj0[KK], kj1[KK], kj2[KK], kj3[KK];
#pragma unroll
  for (int m = 0; m < KK; ++m) {
    kk0[m] = 3.0e38f; kj0[m] = 0x7fffffff;
    kk1[m] = 3.0e38f; kj1[m] = 0x7fffffff;
    kk2[m] = 3.0e38f; kj2[m] = 0x7fffffff;
    kk3[m] = 3.0e38f; kj3[m] = 0x7fffffff;
  }

  __syncthreads();

  for (int jt = 0; jt < NT; ++jt) {
    const int j0 = jbase + (jt << 6);

    // T14: issue next tile's global loads now; LDS write after compute+barrier
    float4 pf0, pf1, pf2, pf3; float psq = 0.f;
    const bool hasNext = (jt + 1 < NT);
    if (hasNext) {
      const float* src = hb + (size_t)(j0 + 64 + tokJ) * DD + dhJ;
      pf0 = *(const float4*)(src);
      pf1 = *(const float4*)(src + 4);
      pf2 = *(const float4*)(src + 8);
      pf3 = *(const float4*)(src + 12);
      if (t < 64) psq = sqb[j0 + 64 + t];
    }

    float acc[4][8];
#pragma unroll
    for (int r = 0; r < 4; ++r)
#pragma unroll
      for (int c = 0; c < 8; ++c) acc[r][c] = 0.f;
#pragma unroll 4
    for (int d = 0; d < DD; ++d) {
      const float4 av = *(const float4*)(&hiT[d][r0]);      // conflict-free b128
      const float4 b0 = *(const float4*)(&hjT[d][c0]);      // 2-way (free)
      const float4 b1 = *(const float4*)(&hjT[d][c0 + 4]);  // 2-way (free)
      const float aa[4] = {av.x, av.y, av.z, av.w};
      const float bb[8] = {b0.x, b0.y, b0.z, b0.w, b1.x, b1.y, b1.z, b1.w};
#pragma unroll
      for (int r = 0; r < 4; ++r)
#pragma unroll
        for (int c = 0; c < 8; ++c) acc[r][c] += aa[r] * bb[c];
    }
    // epilogue: key = fl(fmaf(-2,dot, sqi+sqj) * tau); branchless med3 insert.
    const float4 sj0 = *(const float4*)(&sqjS[c0]);
    const float4 sj1 = *(const float4*)(&sqjS[c0 + 4]);
    const float sj[8] = {sj0.x, sj0.y, sj0.z, sj0.w, sj1.x, sj1.y, sj1.z, sj1.w};
#pragma unroll
    for (int c = 0; c < 8; ++c) {
      const int j = j0 + c0 + c;
      float k0 = __fmul_rn(__builtin_fmaf(-2.0f, acc[0][c], __fadd_rn(sqi0, sj[c])), tau);
      ins_med3(kk0, kj0, k0, j);
      float k1 = __fmul_rn(__builtin_fmaf(-2.0f, acc[1][c], __fadd_rn(sqi1, sj[c])), tau);
      ins_med3(kk1, kj1, k1, j);
      float k2 = __fmul_rn(__builtin_fmaf(-2.0f, acc[2][c], __fadd_rn(sqi2, sj[c])), tau);
      ins_med3(kk2, kj2, k2, j);
      float k3 = __fmul_rn(__builtin_fmaf(-2.0f, acc[3][c], __fadd_rn(sqi3, sj[c])), tau);
      ins_med3(kk3, kj3, k3, j);
    }
    __syncthreads();  // everyone done reading hjT/sqjS
    if (hasNext) {
      scat4j(hjT, dhJ + 0, tokJ, pf0);  scat4j(hjT, dhJ + 4, tokJ, pf1);
      scat4j(hjT, dhJ + 8, tokJ, pf2);  scat4j(hjT, dhJ + 12, tokJ, pf3);
      if (t < 64) sqjS[t] = psq;
    }
    __syncthreads();  // staged tile visible
  }

  // ---- merge: 2 passes of 64 rows each (dump overlays hiT; loop-end barrier) ----
  {
    float* dK = (float*)(smem);
    int*   dJ = (int*)(smem + 16384);
    const int lr = rg << 1;
#pragma unroll
    for (int m = 0; m < KK; ++m) {
      dK[((lr + 0) * 8 + cg) * KK + m] = kk0[m];
      dJ[((lr + 0) * 8 + cg) * KK + m] = kj0[m];
      dK[((lr + 1) * 8 + cg) * KK + m] = kk1[m];
      dJ[((lr + 1) * 8 + cg) * KK + m] = kj1[m];
    }
  }
  merge64(smem, t, 0, b, i0, ch, pk, pj);  // rows r0%4 in {0,1}
  {
    float* dK = (float*)(smem);
    int*   dJ = (int*)(smem + 16384);
    const int lr = rg << 1;
#pragma unroll
    for (int m = 0; m < KK; ++m) {
      dK[((lr + 0) * 8 + cg) * KK + m] = kk2[m];
      dJ[((lr + 0) * 8 + cg) * KK + m] = kj2[m];
      dK[((lr + 1) * 8 + cg) * KK + m] = kk3[m];
      dJ[((lr + 1) * 8 + cg) * KK + m] = kj3[m];
    }
  }
  merge64(smem, t, 2, b, i0, ch, pk, pj);  // rows r0%4 in {2,3}
}

// ------- Kernel 3: merge chunks, recompute dng, emit edges + logprobs -------
__global__ __launch_bounds__(256) void k_final(
    const float* __restrict__ h, const float* __restrict__ pk,
    const int* __restrict__ pj, const float* __restrict__ temp,
    float* __restrict__ out) {
  const int gid = blockIdx.x * 256 + threadIdx.x;  // 0..B*N-1
  const int b = gid >> 12;
  const int i = gid & (NN - 1);
  const float tau = tau_of(temp);

  float fk[KK]; int fj[KK];
#pragma unroll
  for (int m = 0; m < KK; ++m) { fk[m] = 3.0e38f; fj[m] = 0x7fffffff; }
  const size_t base = (size_t)(b * NN + i) * CH * KK;
#pragma unroll
  for (int s = 0; s < CH * KK; ++s) {
    ins_lex(fk, fj, pk[base + s], pj[base + s]);
  }

  const float* hi = h + (size_t)(b * NN + i) * DD;
  float4 xi[16];
#pragma unroll
  for (int q = 0; q < 16; ++q) xi[q] = *reinterpret_cast<const float4*>(hi + (q << 2));

  float* oute = out;
  float* outl = out + (size_t)BB * NN * KK * 2;
#pragma unroll
  for (int m = 0; m < KK; ++m) {
    const int j = fj[m];
    const float* hj = h + (size_t)(b * NN + j) * DD;
    float dng = 0.f;
#pragma unroll
    for (int q = 0; q < 16; ++q) {
      const float4 vj = *reinterpret_cast<const float4*>(hj + (q << 2));
      float dx = xi[q].x - vj.x; dng += dx * dx;
      float dy = xi[q].y - vj.y; dng += dy * dy;
      float dz = xi[q].z - vj.z; dng += dz * dz;
      float dw = xi[q].w - vj.w; dng += dw * dw;
    }
    const size_t e = (size_t)(b * NN + i) * KK + m;
    oute[e * 2 + 0] = (float)j;
    oute[e * 2 + 1] = (float)i;
    outl[e] = -__fmul_rn(dng, tau);
  }
}

extern "C" void kernel_launch(void* const* d_in, const int* in_sizes, int n_in,
                              void* d_out, int out_size, void* d_ws, size_t ws_size,
                              hipStream_t stream) {
  const float* x  = (const float*)d_in[0];
  const float* W1 = (const float*)d_in[1];
  const float* b1 = (const float*)d_in[2];
  const float* W2 = (const float*)d_in[3];
  const float* b2 = (const float*)d_in[4];
  const float* W3 = (const float*)d_in[5];
  const float* b3 = (const float*)d_in[6];
  const float* temp = (const float*)d_in[7];
  (void)in_sizes; (void)n_in; (void)out_size; (void)ws_size;

  float* ws = (float*)d_ws;
  float* h  = ws;                                       // B*N*D
  float* sq = h + (size_t)BB * NN * DD;                 // B*N
  float* pk = sq + (size_t)BB * NN;                     // B*N*CH*K
  int*   pj = (int*)(pk + (size_t)BB * NN * CH * KK);   // B*N*CH*K
  float* out = (float*)d_out;

  k_mlp<<<BB * NN / 64, 256, 0, stream>>>(x, W1, b1, W2, b2, W3, b3, h, sq);
  k_disttopk<<<BB * (NN / IT) * CH, 256, 0, stream>>>(h, sq, temp, pk, pj);
  k_final<<<BB * NN / 256, 256, 0, stream>>>(h, pk, pj, temp, out);
}

// Round 9
// 338.551 us; speedup vs baseline: 1.0775x; 1.0775x over previous
//
#include <hip/hip_runtime.h>
#include <math.h>

#define BB 4
#define NN 4096
#define DD 64
#define KK 8
#define IT 128                  // i-tile rows per block
#define NJT (NN / 64)           // 64 j-tiles of 64 cols

#if defined(__has_builtin)
#if __has_builtin(__builtin_amdgcn_fmed3f)
#define FMED3(a, x, b) __builtin_amdgcn_fmed3f((x), (a), (b))
#endif
#endif
#ifndef FMED3
#define FMED3(a, x, b) fminf(fmaxf((a), (x)), (b))
#endif

__device__ __forceinline__ float tau_of(const float* __restrict__ temp) {
  float tc = temp[0];
  tc = fminf(fmaxf(tc, -5.0f), 5.0f);
  return expf(tc);
}

// Branch-free positional insert into sorted (ascending) top-8.
// All updates read OLD values -> fully parallel. key >= kk[7] is a no-op.
// Equal keys place AFTER incumbents (matches ascending-j arrival semantics).
// NOTE: reference-to-1-D-array signature is load-bearing (SROA).
__device__ __forceinline__ void ins_med3(float (&kk)[KK], int (&kj)[KK], float key, int j) {
  const bool l0 = key < kk[0], l1 = key < kk[1], l2 = key < kk[2], l3 = key < kk[3];
  const bool l4 = key < kk[4], l5 = key < kk[5], l6 = key < kk[6], l7 = key < kk[7];
  kj[7] = l6 ? kj[6] : (l7 ? j : kj[7]);  kk[7] = FMED3(kk[6], key, kk[7]);
  kj[6] = l5 ? kj[5] : (l6 ? j : kj[6]);  kk[6] = FMED3(kk[5], key, kk[6]);
  kj[5] = l4 ? kj[4] : (l5 ? j : kj[5]);  kk[5] = FMED3(kk[4], key, kk[5]);
  kj[4] = l3 ? kj[3] : (l4 ? j : kj[4]);  kk[4] = FMED3(kk[3], key, kk[4]);
  kj[3] = l2 ? kj[2] : (l3 ? j : kj[3]);  kk[3] = FMED3(kk[2], key, kk[3]);
  kj[2] = l1 ? kj[1] : (l2 ? j : kj[2]);  kk[2] = FMED3(kk[1], key, kk[2]);
  kj[1] = l0 ? kj[0] : (l1 ? j : kj[1]);  kk[1] = FMED3(kk[0], key, kk[1]);
  kj[0] = l0 ? j : kj[0];                 kk[0] = fminf(kk[0], key);
}

// lexicographic (key asc, idx asc) insertion — arrival order independent.
__device__ __forceinline__ void ins_lex(float (&kk)[KK], int (&kj)[KK], float key, int j) {
  if (key < kk[KK - 1] || (key == kk[KK - 1] && j < kj[KK - 1])) {
    kk[KK - 1] = key; kj[KK - 1] = j;
#pragma unroll
    for (int m = KK - 1; m > 0; --m) {
      bool sw = (kk[m] < kk[m - 1]) || (kk[m] == kk[m - 1] && kj[m] < kj[m - 1]);
      if (sw) {
        float tk = kk[m]; kk[m] = kk[m - 1]; kk[m - 1] = tk;
        int tj = kj[m]; kj[m] = kj[m - 1]; kj[m - 1] = tj;
      }
    }
  }
}

__device__ __forceinline__ void scat4i(float (*dst)[IT], int d0, int col, const float4& v) {
  dst[d0 + 0][col] = v.x; dst[d0 + 1][col] = v.y; dst[d0 + 2][col] = v.z; dst[d0 + 3][col] = v.w;
}
__device__ __forceinline__ void scat4j(float (*dst)[64], int d0, int col, const float4& v) {
  dst[d0 + 0][col] = v.x; dst[d0 + 1][col] = v.y; dst[d0 + 2][col] = v.z; dst[d0 + 3][col] = v.w;
}

// ---------------- Kernel 1: MLP (3 layers) + row squared norms ----------------
__device__ __forceinline__ void mlp_layer(const float (*bin)[68], float (*bout)[68],
                                          float (*wT)[68], float* bias,
                                          const float* __restrict__ Wg,
                                          const float* __restrict__ bg,
                                          bool dorelu, int t) {
  const int rr = t >> 2;
  const int dc = (t & 3) << 4;
  {
    const float* wsrc = Wg + rr * DD + dc;
#pragma unroll
    for (int q = 0; q < 16; ++q) wT[dc + q][rr] = wsrc[q];  // wT[i][o] = W[o][i]
    if (t < DD) bias[t] = bg[t];
  }
  __syncthreads();
  const int tg = t & 15, og = t >> 4;
  float acc[4][4];
#pragma unroll
  for (int r = 0; r < 4; ++r)
#pragma unroll
    for (int c = 0; c < 4; ++c) acc[r][c] = 0.f;
#pragma unroll 4
  for (int i = 0; i < DD; ++i) {
    const float4 av = *reinterpret_cast<const float4*>(&bin[i][tg << 2]);
    const float4 wv = *reinterpret_cast<const float4*>(&wT[i][og << 2]);
    float aa[4] = {av.x, av.y, av.z, av.w};
    float ww[4] = {wv.x, wv.y, wv.z, wv.w};
#pragma unroll
    for (int r = 0; r < 4; ++r)
#pragma unroll
      for (int c = 0; c < 4; ++c) acc[r][c] += aa[r] * ww[c];
  }
#pragma unroll
  for (int r = 0; r < 4; ++r)
#pragma unroll
    for (int c = 0; c < 4; ++c) {
      float v = acc[r][c] + bias[(og << 2) + c];
      if (dorelu) v = fmaxf(v, 0.f);
      bout[(og << 2) + c][(tg << 2) + r] = v;  // transposed for next layer
    }
  __syncthreads();
}

__global__ __launch_bounds__(256) void k_mlp(
    const float* __restrict__ x,
    const float* __restrict__ W1, const float* __restrict__ b1,
    const float* __restrict__ W2, const float* __restrict__ b2,
    const float* __restrict__ W3, const float* __restrict__ b3,
    float* __restrict__ h, float* __restrict__ sqo) {
  __shared__ float bufA[DD][68];
  __shared__ float bufB[DD][68];
  __shared__ float wT[DD][68];
  __shared__ float bias[DD];
  const int t = threadIdx.x;
  const size_t tok0 = (size_t)blockIdx.x * 64;
  const int rr = t >> 2;
  const int dc = (t & 3) << 4;
  {
    const float* src = x + (tok0 + rr) * DD + dc;
#pragma unroll
    for (int q = 0; q < 16; ++q) bufA[dc + q][rr] = src[q];
  }
  mlp_layer(bufA, bufB, wT, bias, W1, b1, true, t);
  mlp_layer(bufB, bufA, wT, bias, W2, b2, true, t);
  mlp_layer(bufA, bufB, wT, bias, W3, b3, false, t);
  {
    float s = 0.f;
    float* dst = h + (tok0 + rr) * DD + dc;
#pragma unroll
    for (int q = 0; q < 16; ++q) {
      float v = bufB[dc + q][rr];
      dst[q] = v;
      s += v * v;
    }
    s += __shfl_xor(s, 1);
    s += __shfl_xor(s, 2);
    if ((t & 3) == 0) sqo[tok0 + rr] = s;
  }
}

// ---- Kernel 2 helper: merge 64 rows x 8 lane-lists from LDS dump -> pk/pj ----
// Touches ONLY LDS + globals (no register lists) so it can't break SROA.
__device__ __forceinline__ void merge64(char* smem, int t, int rowOff,
                                        int b, int i0, int ch, int nch,
                                        float* __restrict__ pk, int* __restrict__ pj) {
  float* dK = (float*)(smem);            // [64][8][8] keys (16KB)
  int*   dJ = (int*)(smem + 16384);      // [64][8][8] idx  (16KB)
  float* oK = (float*)(smem);            // [64][2][8] keys (4KB, reused after sync)
  int*   oJ = (int*)(smem + 4096);       // [64][2][8] idx  (4KB)
  __syncthreads();  // dump visible
  float fk[KK]; int fj[KK];
#pragma unroll
  for (int m = 0; m < KK; ++m) { fk[m] = 3.0e38f; fj[m] = 0x7fffffff; }
  const int rowA = t >> 1, half = t & 1;
  if (t < 128) {
#pragma unroll
    for (int o = 0; o < 4; ++o)
#pragma unroll
      for (int m = 0; m < KK; ++m)
        ins_lex(fk, fj, dK[(rowA * 8 + half * 4 + o) * KK + m],
                        dJ[(rowA * 8 + half * 4 + o) * KK + m]);
  }
  __syncthreads();  // stage-A reads complete before oK overwrite
  if (t < 128) {
#pragma unroll
    for (int m = 0; m < KK; ++m) {
      oK[(rowA * 2 + half) * KK + m] = fk[m];
      oJ[(rowA * 2 + half) * KK + m] = fj[m];
    }
  }
  __syncthreads();
  if (t < 64) {
    float gk[KK]; int gj[KK];
#pragma unroll
    for (int m = 0; m < KK; ++m) { gk[m] = 3.0e38f; gj[m] = 0x7fffffff; }
#pragma unroll
    for (int q = 0; q < 2; ++q)
#pragma unroll
      for (int m = 0; m < KK; ++m)
        ins_lex(gk, gj, oK[(t * 2 + q) * KK + m], oJ[(t * 2 + q) * KK + m]);
    const int grow = ((t >> 1) << 2) + (t & 1) + rowOff;
    const size_t base = ((size_t)(b * NN + i0 + grow) * nch + ch) * KK;
#pragma unroll
    for (int m = 0; m < KK; ++m) { pk[base + m] = gk[m]; pj[base + m] = gj[m]; }
  }
  __syncthreads();  // protect dK region from the next pass's dump
}

// ------- Kernel 2: 128x64 block tiles, 4x8 register tile, per-row top-8 -------
// nch runtime j-chunks of ~NJT/nch 64-col tiles; grid = BB * 32 * nch.
__global__ __launch_bounds__(256, 3) void k_disttopk(
    const float* __restrict__ h, const float* __restrict__ sq,
    const float* __restrict__ temp, int nch,
    float* __restrict__ pk, int* __restrict__ pj) {
  // LDS: hiT [64][128] @0 (32KB) | hjT [64][64] @32768 (16KB) | sqjS [64] @49152
  __shared__ __align__(16) char smem[32768 + 16384 + 256];
  float (*hiT)[IT] = (float (*)[IT])(smem);
  float (*hjT)[64] = (float (*)[64])(smem + 32768);
  float* sqjS = (float*)(smem + 49152);  // [64]

  const int t = threadIdx.x;
  const int bx = blockIdx.x;
  const int bpb = 32 * nch;       // blocks per batch
  const int b = bx / bpb;
  const int rem = bx - b * bpb;
  const int rt = rem / nch;       // 0..31
  const int ch = rem - rt * nch;  // 0..nch-1
  const int i0 = rt << 7;         // 128-row i-tile
  // unequal chunk of the 64 j-tiles: q = 64/nch, r = 64%nch
  const int q = NJT / nch, rmd = NJT - q * nch;
  const int dt0 = ch * q + (ch < rmd ? ch : rmd);
  const int dt1 = dt0 + q + (ch < rmd ? 1 : 0);
  const float* hb = h + (size_t)b * NN * DD;
  const float* sqb = sq + b * NN;
  const float tau = tau_of(temp);

  const int rg = t >> 3;          // 0..31
  const int cg = t & 7;           // 0..7
  const int r0 = rg << 2;         // 4 rows per thread
  const int c0 = cg << 3;         // 8 cols per thread
  // hjT staging: lane stages 16 d-floats of one token (banks tok%32 -> 2-way, free)
  const int tokJ = t & 63;
  const int dhJ = (t >> 6) << 4;  // 0,16,32,48

  // ---- stage hiT [d][tok], 128 tokens: lane stages 32 d-floats of one token ----
  {
    const int tok = t & 127;
    const int dh = (t >> 7) << 5;  // 0 or 32
    const float* src = hb + (size_t)(i0 + tok) * DD + dh;
    const float4 g0 = *(const float4*)(src);
    const float4 g1 = *(const float4*)(src + 4);
    const float4 g2 = *(const float4*)(src + 8);
    const float4 g3 = *(const float4*)(src + 12);
    const float4 g4 = *(const float4*)(src + 16);
    const float4 g5 = *(const float4*)(src + 20);
    const float4 g6 = *(const float4*)(src + 24);
    const float4 g7 = *(const float4*)(src + 28);
    scat4i(hiT, dh + 0, tok, g0);  scat4i(hiT, dh + 4, tok, g1);
    scat4i(hiT, dh + 8, tok, g2);  scat4i(hiT, dh + 12, tok, g3);
    scat4i(hiT, dh + 16, tok, g4); scat4i(hiT, dh + 20, tok, g5);
    scat4i(hiT, dh + 24, tok, g6); scat4i(hiT, dh + 28, tok, g7);
  }
  // ---- stage hjT tile dt0 + sqjS ----
  {
    const int jb = dt0 << 6;
    const float* src = hb + (size_t)(jb + tokJ) * DD + dhJ;
    const float4 g0 = *(const float4*)(src);
    const float4 g1 = *(const float4*)(src + 4);
    const float4 g2 = *(const float4*)(src + 8);
    const float4 g3 = *(const float4*)(src + 12);
    scat4j(hjT, dhJ + 0, tokJ, g0);  scat4j(hjT, dhJ + 4, tokJ, g1);
    scat4j(hjT, dhJ + 8, tokJ, g2);  scat4j(hjT, dhJ + 12, tokJ, g3);
    if (t < 64) sqjS[t] = sqb[jb + t];
  }
  const float sqi0 = sqb[i0 + r0 + 0];
  const float sqi1 = sqb[i0 + r0 + 1];
  const float sqi2 = sqb[i0 + r0 + 2];
  const float sqi3 = sqb[i0 + r0 + 3];

  float kk0[KK], kk1[KK], kk2[KK], kk3[KK];
  int kj0[KK], kj1[KK], kj2[KK], kj3[KK];
#pragma unroll
  for (int m = 0; m < KK; ++m) {
    kk0[m] = 3.0e38f; kj0[m] = 0x7fffffff;
    kk1[m] = 3.0e38f; kj1[m] = 0x7fffffff;
    kk2[m] = 3.0e38f; kj2[m] = 0x7fffffff;
    kk3[m] = 3.0e38f; kj3[m] = 0x7fffffff;
  }

  __syncthreads();

  for (int dt = dt0; dt < dt1; ++dt) {
    const int j0 = dt << 6;

    // T14: issue next tile's global loads now; LDS write after compute+barrier
    float4 pf0, pf1, pf2, pf3; float psq = 0.f;
    const bool hasNext = (dt + 1 < dt1);
    if (hasNext) {
      const float* src = hb + (size_t)(j0 + 64 + tokJ) * DD + dhJ;
      pf0 = *(const float4*)(src);
      pf1 = *(const float4*)(src + 4);
      pf2 = *(const float4*)(src + 8);
      pf3 = *(const float4*)(src + 12);
      if (t < 64) psq = sqb[j0 + 64 + t];
    }

    float acc[4][8];
#pragma unroll
    for (int r = 0; r < 4; ++r)
#pragma unroll
      for (int c = 0; c < 8; ++c) acc[r][c] = 0.f;
#pragma unroll 4
    for (int d = 0; d < DD; ++d) {
      const float4 av = *(const float4*)(&hiT[d][r0]);      // conflict-free b128
      const float4 b0 = *(const float4*)(&hjT[d][c0]);      // 2-way (free)
      const float4 b1 = *(const float4*)(&hjT[d][c0 + 4]);  // 2-way (free)
      const float aa[4] = {av.x, av.y, av.z, av.w};
      const float bb[8] = {b0.x, b0.y, b0.z, b0.w, b1.x, b1.y, b1.z, b1.w};
#pragma unroll
      for (int r = 0; r < 4; ++r)
#pragma unroll
        for (int c = 0; c < 8; ++c) acc[r][c] += aa[r] * bb[c];
    }
    // epilogue: key = fl(fmaf(-2,dot, sqi+sqj) * tau); branchless med3 insert.
    const float4 sj0 = *(const float4*)(&sqjS[c0]);
    const float4 sj1 = *(const float4*)(&sqjS[c0 + 4]);
    const float sj[8] = {sj0.x, sj0.y, sj0.z, sj0.w, sj1.x, sj1.y, sj1.z, sj1.w};
#pragma unroll
    for (int c = 0; c < 8; ++c) {
      const int j = j0 + c0 + c;
      float k0 = __fmul_rn(__builtin_fmaf(-2.0f, acc[0][c], __fadd_rn(sqi0, sj[c])), tau);
      ins_med3(kk0, kj0, k0, j);
      float k1 = __fmul_rn(__builtin_fmaf(-2.0f, acc[1][c], __fadd_rn(sqi1, sj[c])), tau);
      ins_med3(kk1, kj1, k1, j);
      float k2 = __fmul_rn(__builtin_fmaf(-2.0f, acc[2][c], __fadd_rn(sqi2, sj[c])), tau);
      ins_med3(kk2, kj2, k2, j);
      float k3 = __fmul_rn(__builtin_fmaf(-2.0f, acc[3][c], __fadd_rn(sqi3, sj[c])), tau);
      ins_med3(kk3, kj3, k3, j);
    }
    __syncthreads();  // everyone done reading hjT/sqjS
    if (hasNext) {
      scat4j(hjT, dhJ + 0, tokJ, pf0);  scat4j(hjT, dhJ + 4, tokJ, pf1);
      scat4j(hjT, dhJ + 8, tokJ, pf2);  scat4j(hjT, dhJ + 12, tokJ, pf3);
      if (t < 64) sqjS[t] = psq;
    }
    __syncthreads();  // staged tile visible
  }

  // ---- merge: 2 passes of 64 rows each (dump overlays hiT; loop-end barrier) ----
  {
    float* dK = (float*)(smem);
    int*   dJ = (int*)(smem + 16384);
    const int lr = rg << 1;
#pragma unroll
    for (int m = 0; m < KK; ++m) {
      dK[((lr + 0) * 8 + cg) * KK + m] = kk0[m];
      dJ[((lr + 0) * 8 + cg) * KK + m] = kj0[m];
      dK[((lr + 1) * 8 + cg) * KK + m] = kk1[m];
      dJ[((lr + 1) * 8 + cg) * KK + m] = kj1[m];
    }
  }
  merge64(smem, t, 0, b, i0, ch, nch, pk, pj);  // rows r0%4 in {0,1}
  {
    float* dK = (float*)(smem);
    int*   dJ = (int*)(smem + 16384);
    const int lr = rg << 1;
#pragma unroll
    for (int m = 0; m < KK; ++m) {
      dK[((lr + 0) * 8 + cg) * KK + m] = kk2[m];
      dJ[((lr + 0) * 8 + cg) * KK + m] = kj2[m];
      dK[((lr + 1) * 8 + cg) * KK + m] = kk3[m];
      dJ[((lr + 1) * 8 + cg) * KK + m] = kj3[m];
    }
  }
  merge64(smem, t, 2, b, i0, ch, nch, pk, pj);  // rows r0%4 in {2,3}
}

// ------- Kernel 3: merge chunks, recompute dng, emit edges + logprobs -------
__global__ __launch_bounds__(256) void k_final(
    const float* __restrict__ h, const float* __restrict__ pk,
    const int* __restrict__ pj, const float* __restrict__ temp, int nch,
    float* __restrict__ out) {
  const int gid = blockIdx.x * 256 + threadIdx.x;  // 0..B*N-1
  const int b = gid >> 12;
  const int i = gid & (NN - 1);
  const float tau = tau_of(temp);

  float fk[KK]; int fj[KK];
#pragma unroll
  for (int m = 0; m < KK; ++m) { fk[m] = 3.0e38f; fj[m] = 0x7fffffff; }
  const size_t base = (size_t)(b * NN + i) * nch * KK;
  for (int s = 0; s < nch * KK; ++s) {
    ins_lex(fk, fj, pk[base + s], pj[base + s]);
  }

  const float* hi = h + (size_t)(b * NN + i) * DD;
  float4 xi[16];
#pragma unroll
  for (int q = 0; q < 16; ++q) xi[q] = *reinterpret_cast<const float4*>(hi + (q << 2));

  float* oute = out;
  float* outl = out + (size_t)BB * NN * KK * 2;
#pragma unroll
  for (int m = 0; m < KK; ++m) {
    const int j = fj[m];
    const float* hj = h + (size_t)(b * NN + j) * DD;
    float dng = 0.f;
#pragma unroll
    for (int q = 0; q < 16; ++q) {
      const float4 vj = *reinterpret_cast<const float4*>(hj + (q << 2));
      float dx = xi[q].x - vj.x; dng += dx * dx;
      float dy = xi[q].y - vj.y; dng += dy * dy;
      float dz = xi[q].z - vj.z; dng += dz * dz;
      float dw = xi[q].w - vj.w; dng += dw * dw;
    }
    const size_t e = (size_t)(b * NN + i) * KK + m;
    oute[e * 2 + 0] = (float)j;
    oute[e * 2 + 1] = (float)i;
    outl[e] = -__fmul_rn(dng, tau);
  }
}

extern "C" void kernel_launch(void* const* d_in, const int* in_sizes, int n_in,
                              void* d_out, int out_size, void* d_ws, size_t ws_size,
                              hipStream_t stream) {
  const float* x  = (const float*)d_in[0];
  const float* W1 = (const float*)d_in[1];
  const float* b1 = (const float*)d_in[2];
  const float* W2 = (const float*)d_in[3];
  const float* b2 = (const float*)d_in[4];
  const float* W3 = (const float*)d_in[5];
  const float* b3 = (const float*)d_in[6];
  const float* temp = (const float*)d_in[7];
  (void)in_sizes; (void)n_in; (void)out_size;

  // adaptive chunk count: prefer 6 (3 blocks/CU), fall back to 4 if ws too small
  const size_t baseBytes = (size_t)BB * NN * DD * 4 + (size_t)BB * NN * 4;
  int nch = 6;
  if (baseBytes + (size_t)BB * NN * 6 * KK * 8 > ws_size) nch = 4;

  float* ws = (float*)d_ws;
  float* h  = ws;                                        // B*N*D
  float* sq = h + (size_t)BB * NN * DD;                  // B*N
  float* pk = sq + (size_t)BB * NN;                      // B*N*nch*K
  int*   pj = (int*)(pk + (size_t)BB * NN * nch * KK);   // B*N*nch*K
  float* out = (float*)d_out;

  k_mlp<<<BB * NN / 64, 256, 0, stream>>>(x, W1, b1, W2, b2, W3, b3, h, sq);
  k_disttopk<<<BB * (NN / IT) * nch, 256, 0, stream>>>(h, sq, temp, nch, pk, pj);
  k_final<<<BB * NN / 256, 256, 0, stream>>>(h, pk, pj, temp, nch, out);
}